// Round 1
// baseline (2751.498 us; speedup 1.0000x reference)
//
#include <hip/hip_runtime.h>

typedef short v8s __attribute__((ext_vector_type(8)));
typedef float v4f __attribute__((ext_vector_type(4)));
typedef unsigned short ushort_t;
typedef unsigned int uint_t;

// ---------- helpers ----------
__device__ inline ushort_t f2bf(float f) {
    union { float f; uint_t u; } v; v.f = f;
    uint_t r = v.u + 0x7FFFu + ((v.u >> 16) & 1u);   // RNE
    return (ushort_t)(r >> 16);
}
__device__ inline float sigf(float x) { return 1.f / (1.f + expf(-x)); }

// ---------- lengths ----------
__global__ void k_lens(const int* __restrict__ tc, const int* __restrict__ uh,
                       int* lens_s, int* lens_h, int* lens_c) {
    int t = blockIdx.x * 256 + threadIdx.x;
    if (t < 640) {
        int c = 0;
        for (int s = 0; s < 50; ++s) c += (tc[t * 53 + 3 + s] != 0);
        lens_s[t] = c;
    } else if (t < 2240) {
        int r = t - 640; int c = 0;
        for (int s = 0; s < 50; ++s) c += (uh[r * 50 + s] != 0);
        lens_h[r] = c;
    } else if (t < 2272) {
        int b = t - 2240; int c = 0;
        for (int tt = 0; tt < 20; ++tt) c += (tc[(b * 20 + tt) * 53 + 3] != 0);
        lens_c[b] = c;
    }
}

// ---------- embedding gather -> bf16, K padded 300->320 ----------
__global__ void k_gather(const int* __restrict__ tc, const int* __restrict__ uh,
                         const float* __restrict__ E,
                         ushort_t* __restrict__ Xs, ushort_t* __restrict__ Xh) {
    int r = blockIdx.x; int tid = threadIdx.x;
    int tok; ushort_t* dst;
    if (r < 32000) {
        int sr = r / 50, s = r % 50;
        tok = tc[sr * 53 + 3 + s];
        dst = Xs + (size_t)r * 320;
    } else {
        int rr = r - 32000; int hr = rr / 50, s = rr % 50;
        tok = uh[hr * 50 + s];
        dst = Xh + (size_t)rr * 320;
    }
    const float* Er = E + (size_t)tok * 300;
    for (int d = tid; d < 320; d += 64) dst[d] = (d < 300) ? f2bf(Er[d]) : (ushort_t)0;
}

// ---------- pack A weights into MFMA B-fragment order ----------
// K layout: [0..299]=Wih cols, [300..319]=0, [320..469]=Whh cols, [470..479]=0
// pack idx: ((set*570 + tile*15 + kc)*64 + lane)*8 + j ; set=k*2+dir, tile<38, kc<15
__global__ void k_packA(const float* __restrict__ Wih, const float* __restrict__ Whh,
                        ushort_t* __restrict__ pack) {
    int job = blockIdx.x; int lane = threadIdx.x;
    int set = job / 570; int rem = job % 570; int tile = rem / 15; int kc = rem % 15;
    int n = tile * 16 + (lane & 15);
    int kbase = kc * 32 + (lane >> 4) * 8;
    ushort_t v[8];
#pragma unroll
    for (int j = 0; j < 8; ++j) {
        int k = kbase + j; float f = 0.f;
        if (n < 600) {
            if (k < 300) f = Wih[((size_t)set * 600 + n) * 300 + k];
            else if (k >= 320 && k < 470) f = Whh[((size_t)set * 600 + n) * 150 + (k - 320)];
        }
        v[j] = f2bf(f);
    }
    uint4 u;
    u.x = (uint_t)v[0] | ((uint_t)v[1] << 16);
    u.y = (uint_t)v[2] | ((uint_t)v[3] << 16);
    u.z = (uint_t)v[4] | ((uint_t)v[5] << 16);
    u.w = (uint_t)v[6] | ((uint_t)v[7] << 16);
    *(uint4*)(pack + ((size_t)job * 64 + lane) * 8) = u;
}

// ---------- pack C weights (Din=303) ----------
__global__ void k_packC(const float* __restrict__ Wih, const float* __restrict__ Whh,
                        ushort_t* __restrict__ pack) {
    int job = blockIdx.x; int lane = threadIdx.x;
    int dir = job / 570; int rem = job % 570; int tile = rem / 15; int kc = rem % 15;
    int n = tile * 16 + (lane & 15);
    int kbase = kc * 32 + (lane >> 4) * 8;
    ushort_t v[8];
#pragma unroll
    for (int j = 0; j < 8; ++j) {
        int k = kbase + j; float f = 0.f;
        if (n < 600) {
            if (k < 303) f = Wih[((size_t)dir * 600 + n) * 303 + k];
            else if (k >= 320 && k < 470) f = Whh[((size_t)dir * 600 + n) * 150 + (k - 320)];
        }
        v[j] = f2bf(f);
    }
    uint4 u;
    u.x = (uint_t)v[0] | ((uint_t)v[1] << 16);
    u.y = (uint_t)v[2] | ((uint_t)v[3] << 16);
    u.z = (uint_t)v[4] | ((uint_t)v[5] << 16);
    u.w = (uint_t)v[6] | ((uint_t)v[7] << 16);
    *(uint4*)(pack + ((size_t)job * 64 + lane) * 8) = u;
}

// ---------- bias sums ----------
__global__ void k_bsum(const float* Abih, const float* Abhh,
                       const float* Cbih, const float* Cbhh,
                       float* bsA, float* bsC) {
    int t = blockIdx.x * 256 + threadIdx.x;
    if (t < 3600) bsA[t] = Abih[t] + Abhh[t];
    else if (t < 4800) { int i = t - 3600; bsC[i] = Cbih[i] + Cbhh[i]; }
}

// ---------- fused BiLSTM recurrence over embedded tokens (A family) ----------
// Block = 16 sequences x 1 direction. LDS XH[16][488]: x(0..319) | h(320..469) | 0
__launch_bounds__(256)
__global__ void k_rec_a(const ushort_t* __restrict__ X, const int* __restrict__ lens,
                        const ushort_t* __restrict__ pack, int kidx,
                        const float* __restrict__ bsum, float* __restrict__ out) {
    const int tid = threadIdx.x;
    const int seq0 = blockIdx.x * 16;
    const int dir = blockIdx.y;
    const ushort_t* Wset = pack + (size_t)(kidx * 2 + dir) * 570 * 512;
    const float* bs = bsum + (kidx * 2 + dir) * 600;

    __shared__ ushort_t XH[16][488];
    __shared__ float G[16][616];
    __shared__ float bsl[600];
    __shared__ int lensl[16];
    __shared__ int maxlen_s;

    if (tid < 16) lensl[tid] = lens[seq0 + tid];
    for (int i = tid; i < 16 * 244; i += 256) ((uint_t*)XH)[i] = 0u;
    for (int i = tid; i < 600; i += 256) bsl[i] = bs[i];
    __syncthreads();
    if (tid == 0) {
        int mx = 0;
        for (int i = 0; i < 16; ++i) mx = max(mx, lensl[i]);
        maxlen_s = mx;
    }
    __syncthreads();
    const int maxlen = maxlen_s;
    const int lane = tid & 63, wave = tid >> 6, q = lane >> 4, l16 = lane & 15;
    const int mx_ = tid >> 4, lx = tid & 15;
    const int mylen = lensl[mx_];

    float cst[10], hst[10];
#pragma unroll
    for (int i = 0; i < 10; ++i) { cst[i] = 0.f; hst[i] = 0.f; }

    for (int t = 0; t < maxlen; ++t) {
        // phase 1: gather x rows (fw: t, bw: len-1-t) into XH
        {
            int te = dir ? (mylen - 1 - t) : t;
            te = te < 0 ? 0 : (te > 49 ? 49 : te);
            const ushort_t* src = X + ((size_t)(seq0 + mx_) * 50 + te) * 320;
#pragma unroll
            for (int cc = 0; cc < 3; ++cc) {
                int c = lx + cc * 16;
                if (c < 40) *(uint4*)&XH[mx_][c * 8] = *(const uint4*)(src + c * 8);
            }
        }
        __syncthreads();
        // phase 2: G[16][600] = XH . W^T via MFMA 16x16x32 bf16
        {
            v8s a[15];
#pragma unroll
            for (int kc = 0; kc < 15; ++kc) a[kc] = *(const v8s*)&XH[l16][kc * 32 + q * 8];
            for (int tile = wave; tile < 38; tile += 4) {
                v4f acc = {0.f, 0.f, 0.f, 0.f};
                const ushort_t* wp = Wset + (size_t)tile * 15 * 512 + lane * 8;
#pragma unroll
                for (int kc = 0; kc < 15; ++kc) {
                    v8s b = *(const v8s*)(wp + (size_t)kc * 512);
                    acc = __builtin_amdgcn_mfma_f32_16x16x32_bf16(a[kc], b, acc, 0, 0, 0);
                }
#pragma unroll
                for (int r = 0; r < 4; ++r) G[q * 4 + r][tile * 16 + l16] = acc[r];
            }
        }
        __syncthreads();
        // phase 3: gate nonlinearities + state update (fp32)
        if (t < mylen) {
#pragma unroll
            for (int i = 0; i < 10; ++i) {
                int d = lx + 16 * i;
                if (d < 150) {
                    float gi = G[mx_][d] + bsl[d];
                    float gf = G[mx_][150 + d] + bsl[150 + d];
                    float gg = G[mx_][300 + d] + bsl[300 + d];
                    float go = G[mx_][450 + d] + bsl[450 + d];
                    float c = sigf(gf) * cst[i] + sigf(gi) * tanhf(gg);
                    float h = sigf(go) * tanhf(c);
                    cst[i] = c; hst[i] = h;
                    XH[mx_][320 + d] = f2bf(h);
                }
            }
        }
        __syncthreads();
    }
#pragma unroll
    for (int i = 0; i < 10; ++i) {
        int d = lx + 16 * i;
        if (d < 150) out[(size_t)(seq0 + mx_) * 300 + dir * 150 + d] = hst[i];
    }
}

// ---------- conversation-level BiLSTM (C family), Din=303, T=20 ----------
__launch_bounds__(256)
__global__ void k_rec_c(const float* __restrict__ srep, const int* __restrict__ tc,
                        const int* __restrict__ lens, const ushort_t* __restrict__ pack,
                        const float* __restrict__ bsum, float* __restrict__ out) {
    const int tid = threadIdx.x;
    const int seq0 = blockIdx.x * 16;
    const int dir = blockIdx.y;
    const ushort_t* Wset = pack + (size_t)dir * 570 * 512;
    const float* bs = bsum + dir * 600;

    __shared__ ushort_t XH[16][488];
    __shared__ float G[16][616];
    __shared__ float bsl[600];
    __shared__ int lensl[16];
    __shared__ int maxlen_s;

    if (tid < 16) lensl[tid] = lens[seq0 + tid];
    for (int i = tid; i < 16 * 244; i += 256) ((uint_t*)XH)[i] = 0u;
    for (int i = tid; i < 600; i += 256) bsl[i] = bs[i];
    __syncthreads();
    if (tid == 0) {
        int mx = 0;
        for (int i = 0; i < 16; ++i) mx = max(mx, lensl[i]);
        maxlen_s = mx;
    }
    __syncthreads();
    const int maxlen = maxlen_s;
    const int lane = tid & 63, wave = tid >> 6, q = lane >> 4, l16 = lane & 15;
    const int mx_ = tid >> 4, lx = tid & 15;
    const int mylen = lensl[mx_];

    float cst[10], hst[10];
#pragma unroll
    for (int i = 0; i < 10; ++i) { cst[i] = 0.f; hst[i] = 0.f; }

    for (int t = 0; t < maxlen; ++t) {
        // phase 1: x = [sent_reps(300) | 3 conv feats] -> bf16
        {
            int te = dir ? (mylen - 1 - t) : t;
            te = te < 0 ? 0 : (te > 19 ? 19 : te);
            int b = seq0 + mx_;
            const float* sr = srep + ((size_t)b * 20 + te) * 300;
            for (int d = lx; d < 300; d += 16) XH[mx_][d] = f2bf(sr[d]);
            if (lx < 3) XH[mx_][300 + lx] = f2bf((float)tc[((size_t)b * 20 + te) * 53 + lx]);
        }
        __syncthreads();
        {
            v8s a[15];
#pragma unroll
            for (int kc = 0; kc < 15; ++kc) a[kc] = *(const v8s*)&XH[l16][kc * 32 + q * 8];
            for (int tile = wave; tile < 38; tile += 4) {
                v4f acc = {0.f, 0.f, 0.f, 0.f};
                const ushort_t* wp = Wset + (size_t)tile * 15 * 512 + lane * 8;
#pragma unroll
                for (int kc = 0; kc < 15; ++kc) {
                    v8s b = *(const v8s*)(wp + (size_t)kc * 512);
                    acc = __builtin_amdgcn_mfma_f32_16x16x32_bf16(a[kc], b, acc, 0, 0, 0);
                }
#pragma unroll
                for (int r = 0; r < 4; ++r) G[q * 4 + r][tile * 16 + l16] = acc[r];
            }
        }
        __syncthreads();
        if (t < mylen) {
#pragma unroll
            for (int i = 0; i < 10; ++i) {
                int d = lx + 16 * i;
                if (d < 150) {
                    float gi = G[mx_][d] + bsl[d];
                    float gf = G[mx_][150 + d] + bsl[150 + d];
                    float gg = G[mx_][300 + d] + bsl[300 + d];
                    float go = G[mx_][450 + d] + bsl[450 + d];
                    float c = sigf(gf) * cst[i] + sigf(gi) * tanhf(gg);
                    float h = sigf(go) * tanhf(c);
                    cst[i] = c; hst[i] = h;
                    XH[mx_][320 + d] = f2bf(h);
                }
            }
        }
        __syncthreads();
    }
#pragma unroll
    for (int i = 0; i < 10; ++i) {
        int d = lx + 16 * i;
        if (d < 150) out[(size_t)(seq0 + mx_) * 300 + dir * 150 + d] = hst[i];
    }
}

// ---------- attention hops + output ----------
__global__ void k_attn(const float* __restrict__ reps, const float* __restrict__ u_in,
                       const float* __restrict__ Wout, const float* __restrict__ bout,
                       float* __restrict__ out) {
    const int b = blockIdx.x;
    const int tid = threadIdx.x;
    const int wave = tid >> 6, lane = tid & 63;
    __shared__ float u_l[300];
    __shared__ float dots[64];
    __shared__ float red[4];
    for (int d = tid; d < 300; d += 256) u_l[d] = u_in[b * 300 + d];
    __syncthreads();
    for (int hop = 0; hop < 2; ++hop) {
        const float* R0 = reps + ((size_t)hop * 1600 + b * 50) * 300;
        for (int n = wave; n < 50; n += 4) {
            float p = 0.f;
            for (int d = lane; d < 300; d += 64) p += R0[(size_t)n * 300 + d] * u_l[d];
            for (int off = 32; off > 0; off >>= 1) p += __shfl_down(p, off);
            if (lane == 0) dots[n] = p;
        }
        __syncthreads();
        if (tid < 64) {
            float x = (lane < 50) ? dots[lane] : -3.4e38f;
            float mx = x;
            for (int off = 32; off > 0; off >>= 1) mx = fmaxf(mx, __shfl_down(mx, off));
            mx = __shfl(mx, 0);
            float e = (lane < 50) ? expf(x - mx) : 0.f;
            float s = e;
            for (int off = 32; off > 0; off >>= 1) s += __shfl_down(s, off);
            s = __shfl(s, 0);
            if (lane < 50) dots[lane] = e / s;
        }
        __syncthreads();
        const float* R1 = reps + ((size_t)(hop + 1) * 1600 + b * 50) * 300;
        for (int d = tid; d < 300; d += 256) {
            float s = 0.f;
            for (int n = 0; n < 50; ++n) s += dots[n] * R1[(size_t)n * 300 + d];
            u_l[d] += s;
        }
        __syncthreads();
    }
    float acc = 0.f;
    for (int d = tid; d < 300; d += 256) acc += u_l[d] * Wout[d];
    for (int off = 32; off > 0; off >>= 1) acc += __shfl_down(acc, off);
    if (lane == 0) red[wave] = acc;
    __syncthreads();
    if (tid == 0) {
        float s = red[0] + red[1] + red[2] + red[3] + bout[0];
        out[b] = 1.f / (1.f + expf(-s));
    }
}

// ---------- launch ----------
extern "C" void kernel_launch(void* const* d_in, const int* in_sizes, int n_in,
                              void* d_out, int out_size, void* d_ws, size_t ws_size,
                              hipStream_t stream) {
    (void)in_sizes; (void)n_in; (void)out_size; (void)ws_size;
    const int*   tc   = (const int*)d_in[0];
    const int*   uh   = (const int*)d_in[1];
    const float* E    = (const float*)d_in[2];
    const float* AWih = (const float*)d_in[3];
    const float* AWhh = (const float*)d_in[4];
    const float* Abih = (const float*)d_in[5];
    const float* Abhh = (const float*)d_in[6];
    const float* CWih = (const float*)d_in[7];
    const float* CWhh = (const float*)d_in[8];
    const float* Cbih = (const float*)d_in[9];
    const float* Cbhh = (const float*)d_in[10];
    const float* Wout = (const float*)d_in[11];
    const float* bout = (const float*)d_in[12];
    float* out = (float*)d_out;

    char* ws = (char*)d_ws;
    size_t off = 0;
    auto take = [&](size_t bytes) -> char* {
        char* p = ws + off;
        off = (off + bytes + 255) & ~(size_t)255;
        return p;
    };
    int* lens_s = (int*)take(640 * 4);
    int* lens_h = (int*)take(1600 * 4);
    int* lens_c = (int*)take(32 * 4);
    ushort_t* Xs    = (ushort_t*)take((size_t)32000 * 320 * 2);
    ushort_t* Xh    = (ushort_t*)take((size_t)80000 * 320 * 2);
    ushort_t* packA = (ushort_t*)take((size_t)6 * 570 * 512 * 2);
    ushort_t* packC = (ushort_t*)take((size_t)2 * 570 * 512 * 2);
    float* bsA  = (float*)take(3600 * 4);
    float* bsC  = (float*)take(1200 * 4);
    float* srep = (float*)take((size_t)640 * 300 * 4);
    float* reps = (float*)take((size_t)3 * 1600 * 300 * 4);
    float* ubuf = (float*)take((size_t)32 * 300 * 4);

    k_lens<<<9, 256, 0, stream>>>(tc, uh, lens_s, lens_h, lens_c);
    k_gather<<<112000, 64, 0, stream>>>(tc, uh, E, Xs, Xh);
    k_packA<<<3420, 64, 0, stream>>>(AWih, AWhh, packA);
    k_packC<<<1140, 64, 0, stream>>>(CWih, CWhh, packC);
    k_bsum<<<19, 256, 0, stream>>>(Abih, Abhh, Cbih, Cbhh, bsA, bsC);

    k_rec_a<<<dim3(40, 2), 256, 0, stream>>>(Xs, lens_s, packA, 0, bsA, srep);
    k_rec_a<<<dim3(100, 2), 256, 0, stream>>>(Xh, lens_h, packA, 0, bsA, reps);
    k_rec_a<<<dim3(100, 2), 256, 0, stream>>>(Xh, lens_h, packA, 1, bsA, reps + (size_t)1600 * 300);
    k_rec_a<<<dim3(100, 2), 256, 0, stream>>>(Xh, lens_h, packA, 2, bsA, reps + (size_t)2 * 1600 * 300);
    k_rec_c<<<dim3(2, 2), 256, 0, stream>>>(srep, tc, lens_c, packC, bsC, ubuf);
    k_attn<<<32, 256, 0, stream>>>(reps, ubuf, Wout, bout, out);
}